// Round 1
// baseline (822.095 us; speedup 1.0000x reference)
//
#include <hip/hip_runtime.h>
#include <hip/hip_bf16.h>

#define NN_FIN   5
#define NN_CLUS  256
#define NN_FOU1  128
#define NN_FOU2  256
#define NN_HLIN  256
#define NN_OUTP  10

// ---------------- workspace layout (floats) ----------------
// xs      [N*5]
// cnt     [N]
// deg     [N]
// pooled  [256*128]
// g       [256]
// scal    [2]      (ssq, sasn)
// z_stats [N*16]   (z0..z9, mx, inv_l, d_is, pad3)

// ---------------- Kernel A: edge scatter -------------------
__global__ void k_edge_scatter(const int* __restrict__ ei, const float* __restrict__ ew,
                               const float* __restrict__ x,
                               float* __restrict__ xs, float* __restrict__ cnt,
                               float* __restrict__ deg, int E) {
    int idx = blockIdx.x * blockDim.x + threadIdx.x;
    int stride = gridDim.x * blockDim.x;
    for (int e = idx; e < E; e += stride) {
        int s = ei[e];
        int d = ei[E + e];
        float w = ew[e];
        atomicAdd(&cnt[d], 1.0f);
        atomicAdd(&deg[s], w);
        #pragma unroll
        for (int k = 0; k < 5; k++)
            atomicAdd(&xs[d * 5 + k], x[s * 5 + k]);
    }
}

// ---------------- Kernel B: fused node phase ---------------
// per node: z=[xs/denom, x] (10); mat_s row -> softmax -> S row;
// mat_y row -> relu; accumulate pooled += outer(S,Y); ssq; z_stats.
__launch_bounds__(1024, 1)
__global__ void k_node(const float* __restrict__ x, const float* __restrict__ xs,
                       const float* __restrict__ cnt, const float* __restrict__ deg,
                       const float* __restrict__ W1p, const float* __restrict__ R1p,
                       const float* __restrict__ b1p,
                       const float* __restrict__ W1e, const float* __restrict__ R1e,
                       const float* __restrict__ b1e,
                       float* __restrict__ z_stats, float* __restrict__ pooled,
                       float* __restrict__ scal, int N) {
    __shared__ float Wc[10][256];
    __shared__ float bc[256];
    __shared__ float We[10][128];
    __shared__ float be[128];
    __shared__ float S_t[16][256];
    __shared__ float Y_t[16][128];
    __shared__ float red[16];

    int t = threadIdx.x;
    for (int k = t; k < 10 * 256; k += 1024)
        Wc[k >> 8][k & 255] = (k < 5 * 256) ? W1p[k] : R1p[k - 5 * 256];
    for (int k = t; k < 256; k += 1024) bc[k] = b1p[k];
    for (int k = t; k < 10 * 128; k += 1024)
        We[k >> 7][k & 127] = (k < 5 * 128) ? W1e[k] : R1e[k - 5 * 128];
    for (int k = t; k < 128; k += 1024) be[k] = b1e[k];
    __syncthreads();

    int wave = t >> 6, lane = t & 63;
    int cg = t >> 4, fg = t & 15;   // GEMM mapping: c0=cg*4 (0..63), f0=fg*8 (0..15)

    float acc[4][8] = {{0.f}};
    float ssq_acc = 0.f;

    int ntiles = (N + 15) >> 4;
    for (int tile = blockIdx.x; tile < ntiles; tile += gridDim.x) {
        int i = tile * 16 + wave;
        if (i < N) {
            float z[10];
            float c_ = cnt[i];
            float dn = fmaxf(c_, 1.0f);
            float dg = deg[i];
            #pragma unroll
            for (int d = 0; d < 5; d++) {
                z[d] = xs[i * 5 + d] / dn;
                z[5 + d] = x[i * 5 + d];
            }
            // mat_s (4 cols per lane, stride 64)
            float m[4];
            #pragma unroll
            for (int j = 0; j < 4; j++) {
                int c = lane + 64 * j;
                float v = bc[c];
                #pragma unroll
                for (int d = 0; d < 10; d++) v += z[d] * Wc[d][c];
                m[j] = v;
            }
            float mx = fmaxf(fmaxf(m[0], m[1]), fmaxf(m[2], m[3]));
            #pragma unroll
            for (int o = 32; o > 0; o >>= 1) mx = fmaxf(mx, __shfl_xor(mx, o));
            float e[4], ls = 0.f;
            #pragma unroll
            for (int j = 0; j < 4; j++) { e[j] = __expf(m[j] - mx); ls += e[j]; }
            #pragma unroll
            for (int o = 32; o > 0; o >>= 1) ls += __shfl_xor(ls, o);
            float inv_l = 1.0f / ls;
            float sq = 0.f;
            #pragma unroll
            for (int j = 0; j < 4; j++) {
                float s = e[j] * inv_l;
                S_t[wave][lane + 64 * j] = s;
                sq += s * s;
            }
            if (dg > 0.f) ssq_acc += sq;
            // mat_y (2 cols per lane)
            #pragma unroll
            for (int j = 0; j < 2; j++) {
                int f = lane + 64 * j;
                float v = be[f];
                #pragma unroll
                for (int d = 0; d < 10; d++) v += z[d] * We[d][f];
                Y_t[wave][f] = fmaxf(v, 0.f);
            }
            if (lane == 0) {
                float dis = (dg > 0.f) ? rsqrtf(fmaxf(dg, 1e-30f)) : 0.f;
                float* zp = &z_stats[(size_t)i * 16];
                #pragma unroll
                for (int d = 0; d < 10; d++) zp[d] = z[d];
                zp[10] = mx; zp[11] = inv_l; zp[12] = dis;
                zp[13] = 0.f; zp[14] = 0.f; zp[15] = 0.f;
            }
        } else {
            #pragma unroll
            for (int j = 0; j < 4; j++) S_t[wave][lane + 64 * j] = 0.f;
            #pragma unroll
            for (int j = 0; j < 2; j++) Y_t[wave][lane + 64 * j] = 0.f;
        }
        __syncthreads();
        // mini-GEMM: pooled_partial += S_t^T @ Y_t   (k = 16)
        #pragma unroll
        for (int k = 0; k < 16; k++) {
            float4 sv = *(const float4*)&S_t[k][cg * 4];
            float4 y0 = *(const float4*)&Y_t[k][fg * 8];
            float4 y1 = *(const float4*)&Y_t[k][fg * 8 + 4];
            float sa[4] = {sv.x, sv.y, sv.z, sv.w};
            float yb[8] = {y0.x, y0.y, y0.z, y0.w, y1.x, y1.y, y1.z, y1.w};
            #pragma unroll
            for (int a = 0; a < 4; a++)
                #pragma unroll
                for (int b = 0; b < 8; b++)
                    acc[a][b] += sa[a] * yb[b];
        }
        __syncthreads();
    }

    #pragma unroll
    for (int a = 0; a < 4; a++)
        #pragma unroll
        for (int b = 0; b < 8; b++)
            atomicAdd(&pooled[(cg * 4 + a) * 128 + fg * 8 + b], acc[a][b]);

    #pragma unroll
    for (int o = 32; o > 0; o >>= 1) ssq_acc += __shfl_xor(ssq_acc, o);
    if (lane == 0) red[wave] = ssq_acc;
    __syncthreads();
    if (t == 0) {
        float s = 0.f;
        #pragma unroll
        for (int w2 = 0; w2 < 16; w2++) s += red[w2];
        atomicAdd(&scal[0], s);
    }
}

// ---------------- Kernel C: per-edge regularizer -----------
// sum_e w_e * dis[src]*dis[dst] * <S[src],S[dst]>
// <S_i,S_j> = inv_l_i*inv_l_j * sum_c exp2( log2e*((z_i+z_j).Wc_c + 2b_c - mx_i - mx_j) )
__launch_bounds__(256)
__global__ void k_edge_reg(const int* __restrict__ ei, const float* __restrict__ ew,
                           const float* __restrict__ z_stats,
                           const float* __restrict__ W1p, const float* __restrict__ R1p,
                           const float* __restrict__ b1p,
                           float* __restrict__ scal, int E) {
    __shared__ float Wct[256][12];  // [c][d0..d9, 2b*log2e, pad]
    __shared__ float red[4];
    const float LOG2E = 1.4426950408889634f;
    int t = threadIdx.x;
    {
        int c = t;  // 256 threads, one row each
        #pragma unroll
        for (int d = 0; d < 5; d++) {
            Wct[c][d]     = W1p[d * 256 + c] * LOG2E;
            Wct[c][5 + d] = R1p[d * 256 + c] * LOG2E;
        }
        Wct[c][10] = 2.0f * b1p[c] * LOG2E;
        Wct[c][11] = 0.f;
    }
    __syncthreads();

    float acc = 0.f;
    int idx = blockIdx.x * blockDim.x + t;
    int stride = gridDim.x * blockDim.x;
    for (int e = idx; e < E; e += stride) {
        int s = ei[e];
        int d = ei[E + e];
        float w = ew[e];
        const float4* zs = (const float4*)&z_stats[(size_t)s * 16];
        const float4* zd = (const float4*)&z_stats[(size_t)d * 16];
        float4 a0 = zs[0], a1 = zs[1], a2 = zs[2], a3 = zs[3];
        float4 c0 = zd[0], c1 = zd[1], c2 = zd[2], c3 = zd[3];
        float tt = w * a3.x * c3.x;
        if (tt == 0.f) continue;
        float u[10] = {a0.x + c0.x, a0.y + c0.y, a0.z + c0.z, a0.w + c0.w,
                       a1.x + c1.x, a1.y + c1.y, a1.z + c1.z, a1.w + c1.w,
                       a2.x + c2.x, a2.y + c2.y};
        float mxs = (a2.z + c2.z) * LOG2E;
        float scale = tt * a2.w * c2.w;
        float dsum = 0.f;
        #pragma unroll 2
        for (int c = 0; c < 256; c++) {
            const float4* row = (const float4*)&Wct[c][0];
            float4 w0 = row[0];
            float4 w1 = row[1];
            float4 w2 = row[2];
            float v = w2.z - mxs;
            v += u[0] * w0.x + u[1] * w0.y + u[2] * w0.z + u[3] * w0.w;
            v += u[4] * w1.x + u[5] * w1.y + u[6] * w1.z + u[7] * w1.w;
            v += u[8] * w2.x + u[9] * w2.y;
            dsum += exp2f(v);
        }
        acc += scale * dsum;
    }

    #pragma unroll
    for (int o = 32; o > 0; o >>= 1) acc += __shfl_xor(acc, o);
    int wave = t >> 6, lane = t & 63;
    if (lane == 0) red[wave] = acc;
    __syncthreads();
    if (t == 0) atomicAdd(&scal[1], red[0] + red[1] + red[2] + red[3]);
}

// ---------------- Kernel D1: y2 column sums ----------------
// g[f] = sum_c relu( b2e[f] + sum_k mh[k]*W2e[k][f] + sum_k pooled[c][k]*R2e[k][f] )
__launch_bounds__(256)
__global__ void k_pool2(const float* __restrict__ pooled,
                        const float* __restrict__ W2e, const float* __restrict__ R2e,
                        const float* __restrict__ b2e, float* __restrict__ g) {
    __shared__ float mh[128];
    __shared__ float prow[128];
    int t = threadIdx.x;
    int c = blockIdx.x;
    if (t < 128) {
        float s = 0.f;
        for (int cc = 0; cc < 256; cc++) s += pooled[cc * 128 + t];
        mh[t] = s * (1.0f / 256.0f);
        prow[t] = pooled[c * 128 + t];
    }
    __syncthreads();
    float v = b2e[t];
    for (int k = 0; k < 128; k++)
        v += mh[k] * W2e[k * 256 + t] + prow[k] * R2e[k * 256 + t];
    v = fmaxf(v, 0.f);
    atomicAdd(&g[t], v);
}

// ---------------- Kernel D2: final MLP + output ------------
__launch_bounds__(256)
__global__ void k_final(const float* __restrict__ g,
                        const float* __restrict__ Wl1, const float* __restrict__ bl1,
                        const float* __restrict__ Wl2, const float* __restrict__ bl2,
                        const float* __restrict__ scal, float* __restrict__ out, int N) {
    __shared__ float gs[256];
    __shared__ float h1[256];
    __shared__ float lg[10];
    int t = threadIdx.x;
    gs[t] = g[t];
    __syncthreads();
    float v = bl1[t];
    for (int k = 0; k < 256; k++) v += gs[k] * Wl1[k * 256 + t];
    h1[t] = fmaxf(v, 0.f);
    __syncthreads();
    if (t < 10) {
        float s = bl2[t];
        for (int k = 0; k < 256; k++) s += h1[k] * Wl2[k * 10 + t];
        lg[t] = s;
    }
    __syncthreads();
    if (t == 0) {
        float mx = lg[0];
        for (int j = 1; j < 10; j++) mx = fmaxf(mx, lg[j]);
        float ls = 0.f;
        for (int j = 0; j < 10; j++) ls += __expf(lg[j] - mx);
        float lse = mx + logf(ls);
        for (int j = 0; j < 10; j++) out[j] = lg[j] - lse;
        out[10] = (scal[0] - scal[1]) / (float)N;
    }
}

extern "C" void kernel_launch(void* const* d_in, const int* in_sizes, int n_in,
                              void* d_out, int out_size, void* d_ws, size_t ws_size,
                              hipStream_t stream) {
    const float* x   = (const float*)d_in[0];
    const int*   ei  = (const int*)d_in[1];
    const float* ew  = (const float*)d_in[2];
    const float* W1p = (const float*)d_in[3];
    const float* R1p = (const float*)d_in[4];
    const float* b1p = (const float*)d_in[5];
    const float* W1e = (const float*)d_in[6];
    const float* R1e = (const float*)d_in[7];
    const float* b1e = (const float*)d_in[8];
    // d_in[9..11] = W2p,R2p,b2p : dead (S2 == softmax over size-1 axis == 1)
    const float* W2e = (const float*)d_in[12];
    const float* R2e = (const float*)d_in[13];
    const float* b2e = (const float*)d_in[14];
    const float* Wl1 = (const float*)d_in[15];
    const float* bl1 = (const float*)d_in[16];
    const float* Wl2 = (const float*)d_in[17];
    const float* bl2 = (const float*)d_in[18];
    float* out = (float*)d_out;

    int N = in_sizes[0] / 5;
    int E = in_sizes[1] / 2;

    float* ws = (float*)d_ws;
    float* xs     = ws;                    // N*5
    float* cnt    = xs + (size_t)N * 5;    // N
    float* deg    = cnt + N;               // N
    float* pooled = deg + N;               // 32768
    float* g      = pooled + 256 * 128;    // 256
    float* scal   = g + 256;               // 2
    // pad to 16-float alignment for z_stats
    size_t zoff = (size_t)(scal + 2 - ws);
    zoff = (zoff + 15) & ~(size_t)15;
    float* z_stats = ws + zoff;            // N*16

    // zero accumulators (everything before z_stats)
    hipMemsetAsync(ws, 0, zoff * sizeof(float), stream);

    k_edge_scatter<<<1024, 256, 0, stream>>>(ei, ew, x, xs, cnt, deg, E);
    k_node<<<256, 1024, 0, stream>>>(x, xs, cnt, deg, W1p, R1p, b1p,
                                     W1e, R1e, b1e, z_stats, pooled, scal, N);
    k_edge_reg<<<1024, 256, 0, stream>>>(ei, ew, z_stats, W1p, R1p, b1p, scal, E);
    k_pool2<<<256, 256, 0, stream>>>(pooled, W2e, R2e, b2e, g);
    k_final<<<1, 256, 0, stream>>>(g, Wl1, bl1, Wl2, bl2, scal, out, N);
}

// Round 2
// 553.606 us; speedup vs baseline: 1.4850x; 1.4850x over previous
//
#include <hip/hip_runtime.h>
#include <hip/hip_bf16.h>
#include <hip/hip_fp16.h>

// ---------------- workspace layout (u32 words) ----------------
// xsh   [N*3]  half2 pairs {x0,x1},{x2,x3},{x4,cnt}   (atomic accum, memset 0)
// degh  [N]    half2 {deg, 0}                          (atomic accum, memset 0)
// g     [256]  f32                                     (atomic accum, memset 0)
// scal  [2]    f32 (ssq, sasn)                         (atomic accum, memset 0)
// zh    [N*8]  16 halves/node: z0..z9, mx, inv_l, dis, 0,0,0
// pooled[32768] f32
// parts [nparts*16384] (32768 bf16 per part)

__device__ inline float2 h2f(uint32_t u) {
    __half2 h = *reinterpret_cast<__half2*>(&u);
    return __half22float2(h);
}

// ---------------- Kernel A: edge scatter (packed fp16 atomics) ----
__global__ void k_edge_scatter(const int* __restrict__ ei, const float* __restrict__ ew,
                               const float* __restrict__ x,
                               __half2* __restrict__ xsh, __half2* __restrict__ degh, int E) {
    int idx = blockIdx.x * blockDim.x + threadIdx.x;
    int stride = gridDim.x * blockDim.x;
    for (int e = idx; e < E; e += stride) {
        int s = ei[e];
        int d = ei[E + e];
        float w = ew[e];
        const float* xp = x + (size_t)s * 5;
        float x0 = xp[0], x1 = xp[1], x2 = xp[2], x3 = xp[3], x4 = xp[4];
        unsafeAtomicAdd(&xsh[(size_t)d * 3 + 0], __floats2half2_rn(x0, x1));
        unsafeAtomicAdd(&xsh[(size_t)d * 3 + 1], __floats2half2_rn(x2, x3));
        unsafeAtomicAdd(&xsh[(size_t)d * 3 + 2], __floats2half2_rn(x4, 1.0f));
        unsafeAtomicAdd(&degh[s], __floats2half2_rn(w, 0.0f));
    }
}

// ---------------- Kernel B: fused node phase ----------------------
// tile = 32 nodes; node phase: 32 threads/node (sub = t&31, cols sub+32j);
// GEMM phase: wave owns 16 clusters (broadcast S), lane owns 2 features.
__launch_bounds__(1024)
__global__ void k_node(const float* __restrict__ x,
                       const __half2* __restrict__ xsh, const __half2* __restrict__ degh,
                       const float* __restrict__ W1p, const float* __restrict__ R1p,
                       const float* __restrict__ b1p,
                       const float* __restrict__ W1e, const float* __restrict__ R1e,
                       const float* __restrict__ b1e,
                       uint32_t* __restrict__ zh, __hip_bfloat16* __restrict__ parts,
                       float* __restrict__ scal, int N) {
    __shared__ float S_t[32][256];
    __shared__ float Y_t[32][128];
    __shared__ float red[16];

    int t = threadIdx.x;
    int wv = t >> 6, l = t & 63;
    int nl = t >> 5, sub = t & 31;

    float acc[16][2];
    #pragma unroll
    for (int ci = 0; ci < 16; ci++) { acc[ci][0] = 0.f; acc[ci][1] = 0.f; }
    float ssq = 0.f;

    int ntiles = (N + 31) >> 5;
    for (int tile = blockIdx.x; tile < ntiles; tile += (int)gridDim.x) {
        int i = tile * 32 + nl;
        if (i < N) {
            float2 p0 = __half22float2(xsh[(size_t)i * 3 + 0]);
            float2 p1 = __half22float2(xsh[(size_t)i * 3 + 1]);
            float2 p2 = __half22float2(xsh[(size_t)i * 3 + 2]);
            float dg = __half22float2(degh[i]).x;
            float inv_dn = 1.0f / fmaxf(p2.y, 1.0f);
            float z[10];
            z[0] = p0.x * inv_dn; z[1] = p0.y * inv_dn; z[2] = p1.x * inv_dn;
            z[3] = p1.y * inv_dn; z[4] = p2.x * inv_dn;
            const float* xp = x + (size_t)i * 5;
            z[5] = xp[0]; z[6] = xp[1]; z[7] = xp[2]; z[8] = xp[3]; z[9] = xp[4];
            // mat_s: 8 cols, c = sub + 32*j (conflict-free, coalesced, L1-hot weights)
            float m[8];
            #pragma unroll
            for (int j = 0; j < 8; j++) {
                int c = sub + 32 * j;
                float v = b1p[c];
                #pragma unroll
                for (int d = 0; d < 5; d++) v += z[d] * W1p[d * 256 + c];
                #pragma unroll
                for (int d = 0; d < 5; d++) v += z[5 + d] * R1p[d * 256 + c];
                m[j] = v;
            }
            float mx = m[0];
            #pragma unroll
            for (int j = 1; j < 8; j++) mx = fmaxf(mx, m[j]);
            #pragma unroll
            for (int o = 16; o > 0; o >>= 1) mx = fmaxf(mx, __shfl_xor(mx, o));
            float ls = 0.f;
            #pragma unroll
            for (int j = 0; j < 8; j++) { m[j] = __expf(m[j] - mx); ls += m[j]; }
            #pragma unroll
            for (int o = 16; o > 0; o >>= 1) ls += __shfl_xor(ls, o);
            float inv_l = 1.0f / ls;
            float sq = 0.f;
            #pragma unroll
            for (int j = 0; j < 8; j++) {
                float s = m[j] * inv_l;
                S_t[nl][sub + 32 * j] = s;
                sq += s * s;
            }
            if (dg > 0.f) ssq += sq;
            // mat_y: 4 cols, f = sub + 32*j
            #pragma unroll
            for (int j = 0; j < 4; j++) {
                int f = sub + 32 * j;
                float v = b1e[f];
                #pragma unroll
                for (int d = 0; d < 5; d++) v += z[d] * W1e[d * 128 + f];
                #pragma unroll
                for (int d = 0; d < 5; d++) v += z[5 + d] * R1e[d * 128 + f];
                Y_t[nl][f] = fmaxf(v, 0.f);
            }
            if (sub == 0) {
                float dis = (dg > 0.f) ? rsqrtf(fmaxf(dg, 1e-30f)) : 0.f;
                __half2* zp = (__half2*)(zh + (size_t)i * 8);
                zp[0] = __floats2half2_rn(z[0], z[1]);
                zp[1] = __floats2half2_rn(z[2], z[3]);
                zp[2] = __floats2half2_rn(z[4], z[5]);
                zp[3] = __floats2half2_rn(z[6], z[7]);
                zp[4] = __floats2half2_rn(z[8], z[9]);
                zp[5] = __floats2half2_rn(mx, inv_l);
                zp[6] = __floats2half2_rn(dis, 0.f);
                zp[7] = __floats2half2_rn(0.f, 0.f);
            }
        } else {
            #pragma unroll
            for (int j = 0; j < 8; j++) S_t[nl][sub + 32 * j] = 0.f;
            #pragma unroll
            for (int j = 0; j < 4; j++) Y_t[nl][sub + 32 * j] = 0.f;
        }
        __syncthreads();
        // mini-GEMM: acc[ci][f] += S_t[k][wv*16+ci] * Y_t[k][l*2+f]
        #pragma unroll 4
        for (int k = 0; k < 32; k++) {
            float4 s0 = *(const float4*)&S_t[k][wv * 16 + 0];
            float4 s1 = *(const float4*)&S_t[k][wv * 16 + 4];
            float4 s2 = *(const float4*)&S_t[k][wv * 16 + 8];
            float4 s3 = *(const float4*)&S_t[k][wv * 16 + 12];
            float2 y  = *(const float2*)&Y_t[k][l * 2];
            float sv[16] = {s0.x, s0.y, s0.z, s0.w, s1.x, s1.y, s1.z, s1.w,
                            s2.x, s2.y, s2.z, s2.w, s3.x, s3.y, s3.z, s3.w};
            #pragma unroll
            for (int ci = 0; ci < 16; ci++) {
                acc[ci][0] += sv[ci] * y.x;
                acc[ci][1] += sv[ci] * y.y;
            }
        }
        __syncthreads();
    }

    // coalesced bf16 partial store: part[(wv*16+ci)*128 + l*2 + f]
    __hip_bfloat16* part = parts + (size_t)blockIdx.x * 32768;
    #pragma unroll
    for (int ci = 0; ci < 16; ci++) {
        __hip_bfloat162 pr;
        pr.x = __float2bfloat16(acc[ci][0]);
        pr.y = __float2bfloat16(acc[ci][1]);
        *(__hip_bfloat162*)&part[(size_t)(wv * 16 + ci) * 128 + l * 2] = pr;
    }

    #pragma unroll
    for (int o = 32; o > 0; o >>= 1) ssq += __shfl_xor(ssq, o);
    if (l == 0) red[wv] = ssq;
    __syncthreads();
    if (t == 0) {
        float s = 0.f;
        #pragma unroll
        for (int w2 = 0; w2 < 16; w2++) s += red[w2];
        atomicAdd(&scal[0], s);
    }
}

// ---------------- Kernel B2: reduce partials ----------------------
__global__ void k_reduce(const __hip_bfloat16* __restrict__ parts,
                         float* __restrict__ pooled, int nparts) {
    int idx = blockIdx.x * blockDim.x + threadIdx.x;  // 32768 total
    float s = 0.f;
    for (int p = 0; p < nparts; p++)
        s += __bfloat162float(parts[(size_t)p * 32768 + idx]);
    pooled[idx] = s;
}

// ---------------- Kernel C: per-edge regularizer ------------------
__launch_bounds__(256)
__global__ void k_edge_reg(const int* __restrict__ ei, const float* __restrict__ ew,
                           const uint32_t* __restrict__ zh,
                           const float* __restrict__ W1p, const float* __restrict__ R1p,
                           const float* __restrict__ b1p,
                           float* __restrict__ scal, int E) {
    __shared__ float Wct[256][12];  // [c][d0..d9, 2b*log2e, pad]
    __shared__ float red[4];
    const float LOG2E = 1.4426950408889634f;
    int t = threadIdx.x;
    {
        int c = t;
        #pragma unroll
        for (int d = 0; d < 5; d++) {
            Wct[c][d]     = W1p[d * 256 + c] * LOG2E;
            Wct[c][5 + d] = R1p[d * 256 + c] * LOG2E;
        }
        Wct[c][10] = 2.0f * b1p[c] * LOG2E;
        Wct[c][11] = 0.f;
    }
    __syncthreads();

    float acc = 0.f;
    int idx = blockIdx.x * blockDim.x + t;
    int stride = gridDim.x * blockDim.x;
    for (int e = idx; e < E; e += stride) {
        int s = ei[e];
        int dn = ei[E + e];
        float w = ew[e];
        const uint4* za = (const uint4*)(zh + (size_t)s * 8);
        const uint4* zb = (const uint4*)(zh + (size_t)dn * 8);
        uint4 A0 = za[0], A1 = za[1];
        uint4 B0 = zb[0], B1 = zb[1];
        float2 a0 = h2f(A0.x), a1 = h2f(A0.y), a2 = h2f(A0.z), a3 = h2f(A0.w), a4 = h2f(A1.x);
        float2 am = h2f(A1.y), ad = h2f(A1.z);
        float2 c0 = h2f(B0.x), c1 = h2f(B0.y), c2 = h2f(B0.z), c3 = h2f(B0.w), c4 = h2f(B1.x);
        float2 cm = h2f(B1.y), cd = h2f(B1.z);
        float scale = w * ad.x * cd.x * am.y * cm.y;
        if (scale == 0.f) continue;
        float mxs = (am.x + cm.x) * LOG2E;
        float u[10] = {a0.x + c0.x, a0.y + c0.y, a1.x + c1.x, a1.y + c1.y,
                       a2.x + c2.x, a2.y + c2.y, a3.x + c3.x, a3.y + c3.y,
                       a4.x + c4.x, a4.y + c4.y};
        float dsum = 0.f;
        #pragma unroll 2
        for (int c = 0; c < 256; c++) {
            const float4* row = (const float4*)&Wct[c][0];
            float4 w0 = row[0];
            float4 w1 = row[1];
            float4 w2 = row[2];
            float v = w2.z - mxs;
            v += u[0] * w0.x + u[1] * w0.y + u[2] * w0.z + u[3] * w0.w;
            v += u[4] * w1.x + u[5] * w1.y + u[6] * w1.z + u[7] * w1.w;
            v += u[8] * w2.x + u[9] * w2.y;
            dsum += exp2f(v);
        }
        acc += scale * dsum;
    }

    #pragma unroll
    for (int o = 32; o > 0; o >>= 1) acc += __shfl_xor(acc, o);
    int wave = t >> 6, lane = t & 63;
    if (lane == 0) red[wave] = acc;
    __syncthreads();
    if (t == 0) atomicAdd(&scal[1], red[0] + red[1] + red[2] + red[3]);
}

// ---------------- Kernel D1: y2 column sums -----------------------
__launch_bounds__(256)
__global__ void k_pool2(const float* __restrict__ pooled,
                        const float* __restrict__ W2e, const float* __restrict__ R2e,
                        const float* __restrict__ b2e, float* __restrict__ g) {
    __shared__ float mh[128];
    __shared__ float prow[128];
    int t = threadIdx.x;
    int c = blockIdx.x;
    if (t < 128) {
        float s = 0.f;
        for (int cc = 0; cc < 256; cc++) s += pooled[cc * 128 + t];
        mh[t] = s * (1.0f / 256.0f);
        prow[t] = pooled[c * 128 + t];
    }
    __syncthreads();
    float v = b2e[t];
    for (int k = 0; k < 128; k++)
        v += mh[k] * W2e[k * 256 + t] + prow[k] * R2e[k * 256 + t];
    v = fmaxf(v, 0.f);
    atomicAdd(&g[t], v);
}

// ---------------- Kernel D2: final MLP + output -------------------
__launch_bounds__(256)
__global__ void k_final(const float* __restrict__ g,
                        const float* __restrict__ Wl1, const float* __restrict__ bl1,
                        const float* __restrict__ Wl2, const float* __restrict__ bl2,
                        const float* __restrict__ scal, float* __restrict__ out, int N) {
    __shared__ float gs[256];
    __shared__ float h1[256];
    __shared__ float lg[10];
    int t = threadIdx.x;
    gs[t] = g[t];
    __syncthreads();
    float v = bl1[t];
    for (int k = 0; k < 256; k++) v += gs[k] * Wl1[k * 256 + t];
    h1[t] = fmaxf(v, 0.f);
    __syncthreads();
    if (t < 10) {
        float s = bl2[t];
        for (int k = 0; k < 256; k++) s += h1[k] * Wl2[k * 10 + t];
        lg[t] = s;
    }
    __syncthreads();
    if (t == 0) {
        float mx = lg[0];
        for (int j = 1; j < 10; j++) mx = fmaxf(mx, lg[j]);
        float ls = 0.f;
        for (int j = 0; j < 10; j++) ls += __expf(lg[j] - mx);
        float lse = mx + logf(ls);
        for (int j = 0; j < 10; j++) out[j] = lg[j] - lse;
        out[10] = (scal[0] - scal[1]) / (float)N;
    }
}

extern "C" void kernel_launch(void* const* d_in, const int* in_sizes, int n_in,
                              void* d_out, int out_size, void* d_ws, size_t ws_size,
                              hipStream_t stream) {
    const float* x   = (const float*)d_in[0];
    const int*   ei  = (const int*)d_in[1];
    const float* ew  = (const float*)d_in[2];
    const float* W1p = (const float*)d_in[3];
    const float* R1p = (const float*)d_in[4];
    const float* b1p = (const float*)d_in[5];
    const float* W1e = (const float*)d_in[6];
    const float* R1e = (const float*)d_in[7];
    const float* b1e = (const float*)d_in[8];
    // d_in[9..11] = W2p,R2p,b2p : dead (softmax over size-1 axis == 1)
    const float* W2e = (const float*)d_in[12];
    const float* R2e = (const float*)d_in[13];
    const float* b2e = (const float*)d_in[14];
    const float* Wl1 = (const float*)d_in[15];
    const float* bl1 = (const float*)d_in[16];
    const float* Wl2 = (const float*)d_in[17];
    const float* bl2 = (const float*)d_in[18];
    float* out = (float*)d_out;

    int N = in_sizes[0] / 5;
    int E = in_sizes[1] / 2;

    uint32_t* ws = (uint32_t*)d_ws;
    size_t off = 0;
    __half2* xsh  = (__half2*)(ws + off); off += (size_t)N * 3;
    __half2* degh = (__half2*)(ws + off); off += (size_t)N;
    float* g    = (float*)(ws + off); off += 256;
    float* scal = (float*)(ws + off); off += 2;
    size_t zero_words = off;                       // accumulators to clear
    off = (off + 3) & ~(size_t)3;                  // 16B align
    uint32_t* zh = ws + off; off += (size_t)N * 8;
    off = (off + 3) & ~(size_t)3;
    float* pooled = (float*)(ws + off); off += 32768;
    size_t avail = (ws_size / 4 > off) ? (ws_size / 4 - off) : 0;
    int nparts = (int)(avail / 16384);
    if (nparts > 256) nparts = 256;
    if (nparts < 1) nparts = 1;
    __hip_bfloat16* parts = (__hip_bfloat16*)(ws + off);

    hipMemsetAsync(d_ws, 0, zero_words * 4, stream);

    k_edge_scatter<<<1024, 256, 0, stream>>>(ei, ew, x, xsh, degh, E);
    k_node<<<nparts, 1024, 0, stream>>>(x, xsh, degh, W1p, R1p, b1p,
                                        W1e, R1e, b1e, zh, parts, scal, N);
    k_reduce<<<128, 256, 0, stream>>>(parts, pooled, nparts);
    k_edge_reg<<<1024, 256, 0, stream>>>(ei, ew, zh, W1p, R1p, b1p, scal, E);
    k_pool2<<<256, 256, 0, stream>>>(pooled, W2e, R2e, b2e, g);
    k_final<<<1, 256, 0, stream>>>(g, Wl1, bl1, Wl2, bl2, scal, out, N);
}

// Round 3
// 523.899 us; speedup vs baseline: 1.5692x; 1.0567x over previous
//
#include <hip/hip_runtime.h>
#include <hip/hip_bf16.h>
#include <hip/hip_fp16.h>

// ---------------- workspace layout (u32 words) ----------------
// xsh   [N*3]  half2 pairs {x0,x1},{x2,x3},{x4,cnt}   (atomic accum, memset 0)
// degh  [N]    half2 {deg, 0}                          (atomic accum, memset 0)
// g     [256]  f32                                     (atomic accum, memset 0)
// scal  [2]    f32 (ssq, sasn)                         (atomic accum, memset 0)
// dis   [N]    f32
// Sh    [N*128] u32 = 256 halves/node (S row, permuted layout)
// pooled[32768] f32
// parts [nparts*16384] (32768 bf16 per part)

typedef _Float16 half2v __attribute__((ext_vector_type(2)));

__device__ inline float fdot2u(uint32_t a, uint32_t b, float c) {
#if __has_builtin(__builtin_amdgcn_fdot2)
    return __builtin_amdgcn_fdot2(__builtin_bit_cast(half2v, a),
                                  __builtin_bit_cast(half2v, b), c, false);
#else
    __half2 ha = *reinterpret_cast<__half2*>(&a);
    __half2 hb = *reinterpret_cast<__half2*>(&b);
    float2 fa = __half22float2(ha), fb = __half22float2(hb);
    return c + fa.x * fb.x + fa.y * fb.y;
#endif
}

__device__ inline uint32_t pack_h2(float a, float b) {
    __half2 h = __floats2half2_rn(a, b);
    return *reinterpret_cast<uint32_t*>(&h);
}

// ---------------- Kernel A: edge scatter (packed fp16 atomics) ----
__global__ void k_edge_scatter(const int* __restrict__ ei, const float* __restrict__ ew,
                               const float* __restrict__ x,
                               __half2* __restrict__ xsh, __half2* __restrict__ degh, int E) {
    int idx = blockIdx.x * blockDim.x + threadIdx.x;
    int stride = gridDim.x * blockDim.x;
    for (int e = idx; e < E; e += stride) {
        int s = ei[e];
        int d = ei[E + e];
        float w = ew[e];
        const float* xp = x + (size_t)s * 5;
        float x0 = xp[0], x1 = xp[1], x2 = xp[2], x3 = xp[3], x4 = xp[4];
        unsafeAtomicAdd(&xsh[(size_t)d * 3 + 0], __floats2half2_rn(x0, x1));
        unsafeAtomicAdd(&xsh[(size_t)d * 3 + 1], __floats2half2_rn(x2, x3));
        unsafeAtomicAdd(&xsh[(size_t)d * 3 + 2], __floats2half2_rn(x4, 1.0f));
        unsafeAtomicAdd(&degh[s], __floats2half2_rn(w, 0.0f));
    }
}

// ---------------- Kernel B: fused node phase ----------------------
// tile = 32 nodes; node phase: 32 threads/node (sub = t&31, cols sub+32j);
// GEMM phase: wave owns 16 clusters (broadcast S), lane owns 2 features.
__launch_bounds__(1024)
__global__ void k_node(const float* __restrict__ x,
                       const __half2* __restrict__ xsh, const __half2* __restrict__ degh,
                       const float* __restrict__ W1p, const float* __restrict__ R1p,
                       const float* __restrict__ b1p,
                       const float* __restrict__ W1e, const float* __restrict__ R1e,
                       const float* __restrict__ b1e,
                       uint32_t* __restrict__ Sh, float* __restrict__ dis,
                       __hip_bfloat16* __restrict__ parts,
                       float* __restrict__ scal, int N) {
    __shared__ float S_t[32][256];
    __shared__ float Y_t[32][128];
    __shared__ float red[16];

    int t = threadIdx.x;
    int wv = t >> 6, l = t & 63;
    int nl = t >> 5, sub = t & 31;

    float acc[16][2];
    #pragma unroll
    for (int ci = 0; ci < 16; ci++) { acc[ci][0] = 0.f; acc[ci][1] = 0.f; }
    float ssq = 0.f;

    int ntiles = (N + 31) >> 5;
    for (int tile = blockIdx.x; tile < ntiles; tile += (int)gridDim.x) {
        int i = tile * 32 + nl;
        if (i < N) {
            float2 p0 = __half22float2(xsh[(size_t)i * 3 + 0]);
            float2 p1 = __half22float2(xsh[(size_t)i * 3 + 1]);
            float2 p2 = __half22float2(xsh[(size_t)i * 3 + 2]);
            float dg = __half22float2(degh[i]).x;
            float inv_dn = 1.0f / fmaxf(p2.y, 1.0f);
            float z[10];
            z[0] = p0.x * inv_dn; z[1] = p0.y * inv_dn; z[2] = p1.x * inv_dn;
            z[3] = p1.y * inv_dn; z[4] = p2.x * inv_dn;
            const float* xp = x + (size_t)i * 5;
            z[5] = xp[0]; z[6] = xp[1]; z[7] = xp[2]; z[8] = xp[3]; z[9] = xp[4];
            // mat_s: 8 cols, c = sub + 32*j (conflict-free, coalesced, L1-hot weights)
            float m[8];
            #pragma unroll
            for (int j = 0; j < 8; j++) {
                int c = sub + 32 * j;
                float v = b1p[c];
                #pragma unroll
                for (int d = 0; d < 5; d++) v += z[d] * W1p[d * 256 + c];
                #pragma unroll
                for (int d = 0; d < 5; d++) v += z[5 + d] * R1p[d * 256 + c];
                m[j] = v;
            }
            float mx = m[0];
            #pragma unroll
            for (int j = 1; j < 8; j++) mx = fmaxf(mx, m[j]);
            #pragma unroll
            for (int o = 16; o > 0; o >>= 1) mx = fmaxf(mx, __shfl_xor(mx, o));
            float ls = 0.f;
            #pragma unroll
            for (int j = 0; j < 8; j++) { m[j] = __expf(m[j] - mx); ls += m[j]; }
            #pragma unroll
            for (int o = 16; o > 0; o >>= 1) ls += __shfl_xor(ls, o);
            float inv_l = 1.0f / ls;
            float sq = 0.f;
            #pragma unroll
            for (int j = 0; j < 8; j++) {
                float s = m[j] * inv_l;
                m[j] = s;
                S_t[nl][sub + 32 * j] = s;
                sq += s * s;
            }
            if (dg > 0.f) ssq += sq;
            // store S row as halves (permuted layout: pos = sub*8 + j; dot is
            // permutation-invariant so both edge endpoints match)
            uint4 sp;
            sp.x = pack_h2(m[0], m[1]);
            sp.y = pack_h2(m[2], m[3]);
            sp.z = pack_h2(m[4], m[5]);
            sp.w = pack_h2(m[6], m[7]);
            *(uint4*)&Sh[(size_t)i * 128 + sub * 4] = sp;
            // mat_y: 4 cols, f = sub + 32*j
            #pragma unroll
            for (int j = 0; j < 4; j++) {
                int f = sub + 32 * j;
                float v = b1e[f];
                #pragma unroll
                for (int d = 0; d < 5; d++) v += z[d] * W1e[d * 128 + f];
                #pragma unroll
                for (int d = 0; d < 5; d++) v += z[5 + d] * R1e[d * 128 + f];
                Y_t[nl][f] = fmaxf(v, 0.f);
            }
            if (sub == 0)
                dis[i] = (dg > 0.f) ? rsqrtf(fmaxf(dg, 1e-30f)) : 0.f;
        } else {
            #pragma unroll
            for (int j = 0; j < 8; j++) S_t[nl][sub + 32 * j] = 0.f;
            #pragma unroll
            for (int j = 0; j < 4; j++) Y_t[nl][sub + 32 * j] = 0.f;
        }
        __syncthreads();
        // mini-GEMM: acc[ci][f] += S_t[k][wv*16+ci] * Y_t[k][l*2+f]
        #pragma unroll 4
        for (int k = 0; k < 32; k++) {
            float4 s0 = *(const float4*)&S_t[k][wv * 16 + 0];
            float4 s1 = *(const float4*)&S_t[k][wv * 16 + 4];
            float4 s2 = *(const float4*)&S_t[k][wv * 16 + 8];
            float4 s3 = *(const float4*)&S_t[k][wv * 16 + 12];
            float2 y  = *(const float2*)&Y_t[k][l * 2];
            float sv[16] = {s0.x, s0.y, s0.z, s0.w, s1.x, s1.y, s1.z, s1.w,
                            s2.x, s2.y, s2.z, s2.w, s3.x, s3.y, s3.z, s3.w};
            #pragma unroll
            for (int ci = 0; ci < 16; ci++) {
                acc[ci][0] += sv[ci] * y.x;
                acc[ci][1] += sv[ci] * y.y;
            }
        }
        __syncthreads();
    }

    // coalesced bf16 partial store: part[(wv*16+ci)*128 + l*2 + f]
    __hip_bfloat16* part = parts + (size_t)blockIdx.x * 32768;
    #pragma unroll
    for (int ci = 0; ci < 16; ci++) {
        __hip_bfloat162 pr;
        pr.x = __float2bfloat16(acc[ci][0]);
        pr.y = __float2bfloat16(acc[ci][1]);
        *(__hip_bfloat162*)&part[(size_t)(wv * 16 + ci) * 128 + l * 2] = pr;
    }

    #pragma unroll
    for (int o = 32; o > 0; o >>= 1) ssq += __shfl_xor(ssq, o);
    if (l == 0) red[wv] = ssq;
    __syncthreads();
    if (t == 0) {
        float s = 0.f;
        #pragma unroll
        for (int w2 = 0; w2 < 16; w2++) s += red[w2];
        atomicAdd(&scal[0], s);
    }
}

// ---------------- Kernel B2: reduce partials ----------------------
__global__ void k_reduce(const __hip_bfloat16* __restrict__ parts,
                         float* __restrict__ pooled, int nparts) {
    int idx = blockIdx.x * blockDim.x + threadIdx.x;  // 32768 total
    float s = 0.f;
    for (int p = 0; p < nparts; p++)
        s += __bfloat162float(parts[(size_t)p * 32768 + idx]);
    pooled[idx] = s;
}

// ---------------- Kernel C: per-edge regularizer ------------------
// sasn = sum_e w_e * dis[s] * dis[d] * <S_s, S_d>, S rows stored as f16.
// 16 lanes per edge: lane sub reads 16B chunk sub of each row; fdot2; reduce.
__launch_bounds__(256)
__global__ void k_edge_reg(const int* __restrict__ ei, const float* __restrict__ ew,
                           const uint32_t* __restrict__ Sh, const float* __restrict__ dis,
                           float* __restrict__ scal, int E) {
    __shared__ float red[4];
    int t = threadIdx.x;
    int lane = t & 63;
    int sub = lane & 15;
    int grp = lane >> 4;
    int wv = t >> 6;
    int gw = blockIdx.x * (blockDim.x >> 6) + wv;
    int nwaves = gridDim.x * (blockDim.x >> 6);

    float acc = 0.f;
    for (int base = gw * 4; base < E; base += nwaves * 4) {
        int e = base + grp;
        float dot = 0.f;
        float sc = 0.f;
        if (e < E) {
            int s = ei[e];
            int d = ei[E + e];
            const uint4* pa = (const uint4*)(Sh + (size_t)s * 128) + sub;
            const uint4* pb = (const uint4*)(Sh + (size_t)d * 128) + sub;
            uint4 A = *pa;
            uint4 B = *pb;
            dot = fdot2u(A.x, B.x, dot);
            dot = fdot2u(A.y, B.y, dot);
            dot = fdot2u(A.z, B.z, dot);
            dot = fdot2u(A.w, B.w, dot);
            sc = ew[e] * dis[s] * dis[d];
        }
        #pragma unroll
        for (int o = 8; o > 0; o >>= 1) dot += __shfl_xor(dot, o);
        if (sub == 0) acc += sc * dot;
    }

    #pragma unroll
    for (int o = 32; o > 0; o >>= 1) acc += __shfl_xor(acc, o);
    if (lane == 0) red[wv] = acc;
    __syncthreads();
    if (t == 0) atomicAdd(&scal[1], red[0] + red[1] + red[2] + red[3]);
}

// ---------------- Kernel D1: y2 column sums -----------------------
__launch_bounds__(256)
__global__ void k_pool2(const float* __restrict__ pooled,
                        const float* __restrict__ W2e, const float* __restrict__ R2e,
                        const float* __restrict__ b2e, float* __restrict__ g) {
    __shared__ float mh[128];
    __shared__ float prow[128];
    int t = threadIdx.x;
    int c = blockIdx.x;
    if (t < 128) {
        float s = 0.f;
        for (int cc = 0; cc < 256; cc++) s += pooled[cc * 128 + t];
        mh[t] = s * (1.0f / 256.0f);
        prow[t] = pooled[c * 128 + t];
    }
    __syncthreads();
    float v = b2e[t];
    for (int k = 0; k < 128; k++)
        v += mh[k] * W2e[k * 256 + t] + prow[k] * R2e[k * 256 + t];
    v = fmaxf(v, 0.f);
    atomicAdd(&g[t], v);
}

// ---------------- Kernel D2: final MLP + output -------------------
__launch_bounds__(256)
__global__ void k_final(const float* __restrict__ g,
                        const float* __restrict__ Wl1, const float* __restrict__ bl1,
                        const float* __restrict__ Wl2, const float* __restrict__ bl2,
                        const float* __restrict__ scal, float* __restrict__ out, int N) {
    __shared__ float gs[256];
    __shared__ float h1[256];
    __shared__ float lg[10];
    int t = threadIdx.x;
    gs[t] = g[t];
    __syncthreads();
    float v = bl1[t];
    for (int k = 0; k < 256; k++) v += gs[k] * Wl1[k * 256 + t];
    h1[t] = fmaxf(v, 0.f);
    __syncthreads();
    if (t < 10) {
        float s = bl2[t];
        for (int k = 0; k < 256; k++) s += h1[k] * Wl2[k * 10 + t];
        lg[t] = s;
    }
    __syncthreads();
    if (t == 0) {
        float mx = lg[0];
        for (int j = 1; j < 10; j++) mx = fmaxf(mx, lg[j]);
        float ls = 0.f;
        for (int j = 0; j < 10; j++) ls += __expf(lg[j] - mx);
        float lse = mx + logf(ls);
        for (int j = 0; j < 10; j++) out[j] = lg[j] - lse;
        out[10] = (scal[0] - scal[1]) / (float)N;
    }
}

extern "C" void kernel_launch(void* const* d_in, const int* in_sizes, int n_in,
                              void* d_out, int out_size, void* d_ws, size_t ws_size,
                              hipStream_t stream) {
    const float* x   = (const float*)d_in[0];
    const int*   ei  = (const int*)d_in[1];
    const float* ew  = (const float*)d_in[2];
    const float* W1p = (const float*)d_in[3];
    const float* R1p = (const float*)d_in[4];
    const float* b1p = (const float*)d_in[5];
    const float* W1e = (const float*)d_in[6];
    const float* R1e = (const float*)d_in[7];
    const float* b1e = (const float*)d_in[8];
    // d_in[9..11] = W2p,R2p,b2p : dead (softmax over size-1 axis == 1)
    const float* W2e = (const float*)d_in[12];
    const float* R2e = (const float*)d_in[13];
    const float* b2e = (const float*)d_in[14];
    const float* Wl1 = (const float*)d_in[15];
    const float* bl1 = (const float*)d_in[16];
    const float* Wl2 = (const float*)d_in[17];
    const float* bl2 = (const float*)d_in[18];
    float* out = (float*)d_out;

    int N = in_sizes[0] / 5;
    int E = in_sizes[1] / 2;

    uint32_t* ws = (uint32_t*)d_ws;
    size_t off = 0;
    __half2* xsh  = (__half2*)(ws + off); off += (size_t)N * 3;
    __half2* degh = (__half2*)(ws + off); off += (size_t)N;
    float* g    = (float*)(ws + off); off += 256;
    float* scal = (float*)(ws + off); off += 2;
    size_t zero_words = off;                       // accumulators to clear
    off = (off + 3) & ~(size_t)3;                  // 16B align
    float* dis = (float*)(ws + off); off += N;
    off = (off + 3) & ~(size_t)3;
    uint32_t* Sh = ws + off; off += (size_t)N * 128;
    float* pooled = (float*)(ws + off); off += 32768;
    size_t avail = (ws_size / 4 > off) ? (ws_size / 4 - off) : 0;
    int nparts = (int)(avail / 16384);
    if (nparts > 256) nparts = 256;
    if (nparts < 1) nparts = 1;
    __hip_bfloat16* parts = (__hip_bfloat16*)(ws + off);

    hipMemsetAsync(d_ws, 0, zero_words * 4, stream);

    int sgrid = (E + 255) / 256;
    k_edge_scatter<<<sgrid, 256, 0, stream>>>(ei, ew, x, xsh, degh, E);
    k_node<<<nparts, 1024, 0, stream>>>(x, xsh, degh, W1p, R1p, b1p,
                                        W1e, R1e, b1e, Sh, dis, parts, scal, N);
    k_reduce<<<128, 256, 0, stream>>>(parts, pooled, nparts);
    k_edge_reg<<<2048, 256, 0, stream>>>(ei, ew, Sh, dis, scal, E);
    k_pool2<<<256, 256, 0, stream>>>(pooled, W2e, R2e, b2e, g);
    k_final<<<1, 256, 0, stream>>>(g, Wl1, bl1, Wl2, bl2, scal, out, N);
}